// Round 1
// baseline (1187.011 us; speedup 1.0000x reference)
//
#include <hip/hip_runtime.h>
#include <hip/hip_bf16.h>
#include <math.h>

// Problem constants
#define T_TOK 4096   // B*S tokens
#define D_IN  1024
#define H_DIM 2048
#define O_DIM 1024
#define NE    8
#define ROWCAP 8704  // 8192 routed rows + per-expert pad to 64
#define RT_MAX 136   // ROWCAP/64 row tiles

typedef __bf16 bf16x8 __attribute__((ext_vector_type(8)));
typedef __bf16 bf16x4 __attribute__((ext_vector_type(4)));
typedef float  f32x4  __attribute__((ext_vector_type(4)));

// ---------------- gating: raw_gates (fp64), top-2, softmax, aux sums; x->bf16 ----------------
__global__ __launch_bounds__(256) void gating_kernel(
    const float* __restrict__ x, const float* __restrict__ Wg, const float* __restrict__ bg,
    __bf16* __restrict__ xb, float* __restrict__ gates_tk, int* __restrict__ idx_tk,
    int* __restrict__ counts, double* __restrict__ prob_sums, double* __restrict__ count_sums)
{
    __shared__ float xs[D_IN];
    __shared__ double rg[NE];
    const int t = blockIdx.x;
    const int tid = threadIdx.x;
    for (int i = tid; i < D_IN; i += 256) {
        float v = x[(size_t)t * D_IN + i];
        xs[i] = v;
        xb[(size_t)t * D_IN + i] = (__bf16)v;
    }
    __syncthreads();
    const int wave = tid >> 6, lane = tid & 63;
    for (int e = wave * 2; e < wave * 2 + 2; ++e) {
        double s = 0.0;
        for (int i = lane; i < D_IN; i += 64)
            s += (double)xs[i] * (double)Wg[i * NE + e];
        for (int off = 32; off; off >>= 1) s += __shfl_down(s, off);
        if (lane == 0) rg[e] = s + (double)bg[e];
    }
    __syncthreads();
    if (tid == 0) {
        // top-2 (strict >, first index wins ties — matches lax.top_k)
        int i0 = 0;
        for (int e = 1; e < NE; ++e) if (rg[e] > rg[i0]) i0 = e;
        int i1 = -1;
        for (int e = 0; e < NE; ++e) {
            if (e == i0) continue;
            if (i1 < 0 || rg[e] > rg[i1]) i1 = e;
        }
        double v0 = rg[i0], v1 = rg[i1];
        double e0 = exp(0.0), e1 = exp(v1 - v0);  // shift by max (v0)
        double den = e0 + e1;
        float g0 = (float)(e0 / den), g1 = (float)(e1 / den);
        gates_tk[t * 2] = g0; gates_tk[t * 2 + 1] = g1;
        idx_tk[t * 2] = i0;   idx_tk[t * 2 + 1] = i1;
        atomicAdd(&counts[i0], 1);
        atomicAdd(&counts[i1], 1);
        atomicAdd(&count_sums[i0], (double)g0);
        atomicAdd(&count_sums[i1], (double)g1);
        // full softmax over 8 for aux losses
        double mx = rg[0];
        for (int e = 1; e < NE; ++e) mx = fmax(mx, rg[e]);
        double pe[NE]; double sum = 0.0;
        for (int e = 0; e < NE; ++e) { pe[e] = exp(rg[e] - mx); sum += pe[e]; }
        for (int e = 0; e < NE; ++e) atomicAdd(&prob_sums[e], pe[e] / sum);
    }
}

// ---------------- routing: padded prefix sums + tail fill ----------------
__global__ void build_offsets(const int* __restrict__ counts, int* __restrict__ poffset,
                              int* __restrict__ totalp, int* __restrict__ token_ids)
{
    __shared__ int po[NE + 1];
    __shared__ int cnt[NE];
    const int tid = threadIdx.x;
    if (tid == 0) {
        po[0] = 0;
        for (int e = 0; e < NE; ++e) {
            cnt[e] = counts[e];
            int pc = (cnt[e] + 63) & ~63;
            po[e + 1] = po[e] + pc;
        }
        for (int e = 0; e <= NE; ++e) poffset[e] = po[e];
        totalp[0] = po[NE];
    }
    __syncthreads();
    // fill padded tail rows with token 0 (their outputs are never combined)
    for (int e = 0; e < NE; ++e) {
        int base = po[e], c = cnt[e], pc = po[e + 1] - po[e];
        for (int i = c + tid; i < pc; i += 64) token_ids[base + i] = 0;
    }
}

__global__ __launch_bounds__(256) void scatter_rows(
    const int* __restrict__ idx_tk, const int* __restrict__ poffset,
    int* __restrict__ cursors, int* __restrict__ token_ids, int* __restrict__ t2r)
{
    int t = blockIdx.x * 256 + threadIdx.x;
    if (t >= T_TOK) return;
    for (int k = 0; k < 2; ++k) {
        int e = idx_tk[t * 2 + k];
        int pos = atomicAdd(&cursors[e], 1);
        int r = poffset[e] + pos;
        token_ids[r] = t;
        t2r[t * 2 + k] = r;
    }
}

// ---------------- expert GEMM: C[64x64] tiles, bf16 MFMA 16x16x32, fp32 weights converted on stage ----------------
template<bool GATHER, bool RELU, bool OUTBF16>
__global__ __launch_bounds__(256) void gemm_expert(
    const __bf16* __restrict__ A, int lda,
    const float* __restrict__ B, int Kdim, int N,
    const float* __restrict__ bias,
    void* __restrict__ Out, int ldo,
    const int* __restrict__ token_ids,
    const int* __restrict__ poffset,
    const int* __restrict__ totalp)
{
    __shared__ __bf16 As[64][72];  // +8 pad: keeps 16B align, kills bank conflicts
    __shared__ __bf16 Bt[64][72];  // transposed: Bt[n][k]
    const int tid = threadIdx.x;
    const int row0 = blockIdx.y * 64;
    if (row0 >= totalp[0]) return;
    int e = 0;
    while (e < NE - 1 && row0 >= poffset[e + 1]) ++e;
    const int n0 = blockIdx.x * 64;
    const float* Be = B + (size_t)e * Kdim * N;
    const float* biase = bias + (size_t)e * N;

    // A staging: each thread loads 16 bf16 of one row
    const int arow = tid >> 2;
    const int aseg = tid & 3;
    const int asrc_row = GATHER ? token_ids[row0 + arow] : (row0 + arow);
    const __bf16* aptr = A + (size_t)asrc_row * lda + aseg * 16;

    // B staging: thread handles 4 k-rows x 4 n-cols (transpose + fp32->bf16)
    const int kb = tid >> 4;
    const int nb = tid & 15;

    const int lane = tid & 63;
    const int quad = lane >> 4;
    const int m16  = lane & 15;
    const int wave = tid >> 6;
    const int wm = wave >> 1, wn = wave & 1;

    f32x4 acc[2][2];
    #pragma unroll
    for (int i = 0; i < 2; ++i)
        #pragma unroll
        for (int j = 0; j < 2; ++j)
            acc[i][j] = (f32x4){0.f, 0.f, 0.f, 0.f};

    const int niter = Kdim >> 6;
    for (int kt = 0; kt < niter; ++kt) {
        __syncthreads();
        {
            const uint4* p = (const uint4*)(aptr + kt * 64);
            uint4 v0 = p[0];
            uint4 v1 = p[1];
            *(uint4*)&As[arow][aseg * 16]     = v0;
            *(uint4*)&As[arow][aseg * 16 + 8] = v1;
        }
        {
            const size_t kbase = (size_t)(kt * 64 + kb * 4) * N + n0 + nb * 4;
            float4 f0 = *(const float4*)&Be[kbase];
            float4 f1 = *(const float4*)&Be[kbase + N];
            float4 f2 = *(const float4*)&Be[kbase + 2 * (size_t)N];
            float4 f3 = *(const float4*)&Be[kbase + 3 * (size_t)N];
            bf16x4 w0 = {(__bf16)f0.x, (__bf16)f1.x, (__bf16)f2.x, (__bf16)f3.x};
            bf16x4 w1 = {(__bf16)f0.y, (__bf16)f1.y, (__bf16)f2.y, (__bf16)f3.y};
            bf16x4 w2 = {(__bf16)f0.z, (__bf16)f1.z, (__bf16)f2.z, (__bf16)f3.z};
            bf16x4 w3 = {(__bf16)f0.w, (__bf16)f1.w, (__bf16)f2.w, (__bf16)f3.w};
            *(bf16x4*)&Bt[nb * 4 + 0][kb * 4] = w0;
            *(bf16x4*)&Bt[nb * 4 + 1][kb * 4] = w1;
            *(bf16x4*)&Bt[nb * 4 + 2][kb * 4] = w2;
            *(bf16x4*)&Bt[nb * 4 + 3][kb * 4] = w3;
        }
        __syncthreads();
        #pragma unroll
        for (int ks = 0; ks < 2; ++ks) {
            bf16x8 a0 = *(const bf16x8*)&As[wm * 32 + m16][ks * 32 + quad * 8];
            bf16x8 a1 = *(const bf16x8*)&As[wm * 32 + 16 + m16][ks * 32 + quad * 8];
            bf16x8 b0 = *(const bf16x8*)&Bt[wn * 32 + m16][ks * 32 + quad * 8];
            bf16x8 b1 = *(const bf16x8*)&Bt[wn * 32 + 16 + m16][ks * 32 + quad * 8];
            acc[0][0] = __builtin_amdgcn_mfma_f32_16x16x32_bf16(a0, b0, acc[0][0], 0, 0, 0);
            acc[0][1] = __builtin_amdgcn_mfma_f32_16x16x32_bf16(a0, b1, acc[0][1], 0, 0, 0);
            acc[1][0] = __builtin_amdgcn_mfma_f32_16x16x32_bf16(a1, b0, acc[1][0], 0, 0, 0);
            acc[1][1] = __builtin_amdgcn_mfma_f32_16x16x32_bf16(a1, b1, acc[1][1], 0, 0, 0);
        }
    }
    // epilogue: C/D layout col=lane&15, row=quad*4+reg (verified m89/m91)
    #pragma unroll
    for (int i = 0; i < 2; ++i)
        #pragma unroll
        for (int j = 0; j < 2; ++j)
            #pragma unroll
            for (int r = 0; r < 4; ++r) {
                int grow = row0 + wm * 32 + i * 16 + quad * 4 + r;
                int gcol = n0 + wn * 32 + j * 16 + m16;
                float v = acc[i][j][r] + biase[gcol];
                if (RELU) v = v > 0.f ? v : 0.f;
                if (OUTBF16) ((__bf16*)Out)[(size_t)grow * ldo + gcol] = (__bf16)v;
                else         ((float*)Out)[(size_t)grow * ldo + gcol] = v;
            }
}

// ---------------- combine: out[t] = g0*y[r0] + g1*y[r1] ----------------
__global__ __launch_bounds__(256) void combine_out(
    const float* __restrict__ y, const float* __restrict__ gates_tk,
    const int* __restrict__ t2r, float* __restrict__ out)
{
    const int t = blockIdx.x;
    const int o = threadIdx.x * 4;
    const int r0 = t2r[t * 2], r1 = t2r[t * 2 + 1];
    const float g0 = gates_tk[t * 2], g1 = gates_tk[t * 2 + 1];
    float4 a = *(const float4*)&y[(size_t)r0 * O_DIM + o];
    float4 b = *(const float4*)&y[(size_t)r1 * O_DIM + o];
    float4 c;
    c.x = g0 * a.x + g1 * b.x;
    c.y = g0 * a.y + g1 * b.y;
    c.z = g0 * a.z + g1 * b.z;
    c.w = g0 * a.w + g1 * b.w;
    *(float4*)&out[(size_t)t * O_DIM + o] = c;
}

// ---------------- finalize aux outputs ----------------
__global__ void finalize_kernel(const double* __restrict__ prob_sums,
                                const double* __restrict__ count_sums,
                                float* __restrict__ out)
{
    if (threadIdx.x == 0 && blockIdx.x == 0) {
        double lb = 0.0, ent = 0.0;
        for (int e = 0; e < NE; ++e) {
            double p = prob_sums[e] / (double)T_TOK;
            double c = count_sums[e] / (double)T_TOK;
            lb += p * c;
            ent -= p * log(p + 1e-8);
            out[(size_t)T_TOK * O_DIM + 1 + e] = (float)c;
        }
        out[(size_t)T_TOK * O_DIM] = (float)(0.01 * 8.0 * lb);
        out[(size_t)T_TOK * O_DIM + 9] = (float)ent;
    }
}

// ---------------- launch ----------------
extern "C" void kernel_launch(void* const* d_in, const int* in_sizes, int n_in,
                              void* d_out, int out_size, void* d_ws, size_t ws_size,
                              hipStream_t stream)
{
    const float* x  = (const float*)d_in[0];
    const float* Wg = (const float*)d_in[1];
    const float* bg = (const float*)d_in[2];
    const float* W1 = (const float*)d_in[3];
    const float* b1 = (const float*)d_in[4];
    const float* W2 = (const float*)d_in[5];
    const float* b2 = (const float*)d_in[6];
    const float* W3 = (const float*)d_in[7];
    const float* b3 = (const float*)d_in[8];
    float* out = (float*)d_out;
    char* ws = (char*)d_ws;

    // workspace layout (~80 MB)
    __bf16* xb = (__bf16*)(ws + 0);                       //  8,388,608 B
    __bf16* h1 = (__bf16*)(ws + 8388608);                 // 35,651,584 B
    float*  y  = (float*) (ws + 8388608);                 // aliases h1 (dead after layer2)
    __bf16* h2 = (__bf16*)(ws + 44040192);                // 35,651,584 B
    float* gates_tk = (float*)(ws + 79691776);            // 32 KB
    int* idx_tk     = (int*)(ws + 79724544);              // 32 KB
    int* t2r        = (int*)(ws + 79757312);              // 32 KB
    int* token_ids  = (int*)(ws + 79790080);              // 34,816 B
    char* small     = ws + 79824896;                      // 256 B control block
    int* counts     = (int*)(small + 0);
    int* cursors    = (int*)(small + 32);
    int* poffset    = (int*)(small + 64);
    int* totalp     = (int*)(small + 112);
    double* prob_sums  = (double*)(small + 128);
    double* count_sums = (double*)(small + 192);

    hipMemsetAsync(small, 0, 256, stream);
    gating_kernel<<<T_TOK, 256, 0, stream>>>(x, Wg, bg, xb, gates_tk, idx_tk,
                                             counts, prob_sums, count_sums);
    build_offsets<<<1, 64, 0, stream>>>(counts, poffset, totalp, token_ids);
    scatter_rows<<<16, 256, 0, stream>>>(idx_tk, poffset, cursors, token_ids, t2r);
    gemm_expert<true,  true,  true ><<<dim3(H_DIM / 64, RT_MAX), 256, 0, stream>>>(
        xb, D_IN, W1, D_IN, H_DIM, b1, (void*)h1, H_DIM, token_ids, poffset, totalp);
    gemm_expert<false, true,  true ><<<dim3(H_DIM / 64, RT_MAX), 256, 0, stream>>>(
        h1, H_DIM, W2, H_DIM, H_DIM, b2, (void*)h2, H_DIM, token_ids, poffset, totalp);
    gemm_expert<false, false, false><<<dim3(O_DIM / 64, RT_MAX), 256, 0, stream>>>(
        h2, H_DIM, W3, H_DIM, O_DIM, b3, (void*)y, O_DIM, token_ids, poffset, totalp);
    combine_out<<<T_TOK, 256, 0, stream>>>(y, gates_tk, t2r, out);
    finalize_kernel<<<1, 1, 0, stream>>>(prob_sums, count_sums, out);
}

// Round 2
// 883.173 us; speedup vs baseline: 1.3440x; 1.3440x over previous
//
#include <hip/hip_runtime.h>
#include <hip/hip_bf16.h>
#include <math.h>

// Problem constants
#define T_TOK 4096   // B*S tokens
#define D_IN  1024
#define H_DIM 2048
#define O_DIM 1024
#define NE    8
#define ROWCAP 9216  // 8192 routed rows + per-expert pad to 128
#define RT128  72    // ROWCAP/128 row tiles

typedef __bf16 bf16x8 __attribute__((ext_vector_type(8)));
typedef __bf16 bf16x4 __attribute__((ext_vector_type(4)));
typedef float  f32x4  __attribute__((ext_vector_type(4)));

// ---------------- gating: one token per thread, fp64 accumulate, no global fp64 atomics ----------------
__global__ __launch_bounds__(64) void gating_kernel(
    const float* __restrict__ x, const float* __restrict__ Wg, const float* __restrict__ bg,
    __bf16* __restrict__ xb, float* __restrict__ gates_tk, int* __restrict__ idx_tk,
    int* __restrict__ counts, double* __restrict__ prob_part, double* __restrict__ gsum_part)
{
    __shared__ float WgS[D_IN * NE];      // 32 KB
    __shared__ float bgS[NE];
    __shared__ double tok_p[64][NE];      // per-token full softmax probs
    __shared__ double tok_g[64][2];       // per-token top-2 gates
    __shared__ int    tok_i[64][2];       // per-token top-2 indices
    const int tid = threadIdx.x;          // 64 threads

    // stage Wg ([D][E] row-major, as-is) + bg
    for (int i = tid * 4; i < D_IN * NE; i += 64 * 4)
        *(float4*)&WgS[i] = *(const float4*)&Wg[i];
    if (tid < NE) bgS[tid] = bg[tid];

    // coalesced x -> bf16 conversion for this block's 64-token slab
    {
        const size_t base = (size_t)blockIdx.x * 64 * D_IN;
        for (int i = tid * 4; i < 64 * D_IN; i += 64 * 4) {
            float4 v = *(const float4*)(x + base + i);
            bf16x4 b = {(__bf16)v.x, (__bf16)v.y, (__bf16)v.z, (__bf16)v.w};
            *(bf16x4*)(xb + base + i) = b;
        }
    }
    __syncthreads();

    // per-thread token: fp64 dot over 1024 dims x 8 experts (LDS reads are wave-uniform -> broadcast)
    const int t = blockIdx.x * 64 + tid;
    const float* xr = x + (size_t)t * D_IN;
    double s[NE] = {0, 0, 0, 0, 0, 0, 0, 0};
    for (int j = 0; j < D_IN; j += 4) {
        float4 xv = *(const float4*)(xr + j);
        const float* w0 = &WgS[j * NE];
        #pragma unroll
        for (int jj = 0; jj < 4; ++jj) {
            double xd = (double)((&xv.x)[jj]);
            #pragma unroll
            for (int e = 0; e < NE; ++e)
                s[e] += xd * (double)w0[jj * NE + e];
        }
    }
    double rg[NE];
    #pragma unroll
    for (int e = 0; e < NE; ++e) rg[e] = s[e] + (double)bgS[e];

    // top-2 (strict >, first index wins ties — matches lax.top_k)
    int i0 = 0;
    #pragma unroll
    for (int e = 1; e < NE; ++e) if (rg[e] > rg[i0]) i0 = e;
    int i1 = -1;
    #pragma unroll
    for (int e = 0; e < NE; ++e) {
        if (e == i0) continue;
        if (i1 < 0 || rg[e] > rg[i1]) i1 = e;
    }
    double e1 = exp(rg[i1] - rg[i0]);
    double den = 1.0 + e1;
    float g0 = (float)(1.0 / den), g1 = (float)(e1 / den);
    gates_tk[t * 2] = g0; gates_tk[t * 2 + 1] = g1;
    idx_tk[t * 2] = i0;   idx_tk[t * 2 + 1] = i1;
    tok_g[tid][0] = 1.0 / den; tok_g[tid][1] = e1 / den;
    tok_i[tid][0] = i0;        tok_i[tid][1] = i1;

    // full softmax over 8 for aux losses
    double mx = rg[0];
    #pragma unroll
    for (int e = 1; e < NE; ++e) mx = fmax(mx, rg[e]);
    double pe[NE], sum = 0.0;
    #pragma unroll
    for (int e = 0; e < NE; ++e) { pe[e] = exp(rg[e] - mx); sum += pe[e]; }
    #pragma unroll
    for (int e = 0; e < NE; ++e) tok_p[tid][e] = pe[e] / sum;

    __syncthreads();
    if (tid < NE) {
        double p = 0.0, g = 0.0; int c = 0;
        for (int i = 0; i < 64; ++i) {
            p += tok_p[i][tid];
            if (tok_i[i][0] == tid) { g += tok_g[i][0]; ++c; }
            if (tok_i[i][1] == tid) { g += tok_g[i][1]; ++c; }
        }
        prob_part[blockIdx.x * NE + tid] = p;
        gsum_part[blockIdx.x * NE + tid] = g;
        atomicAdd(&counts[tid], c);
    }
}

// ---------------- routing: padded (to 128) prefix sums + tail fill ----------------
__global__ void build_offsets(const int* __restrict__ counts, int* __restrict__ poffset,
                              int* __restrict__ totalp, int* __restrict__ token_ids)
{
    __shared__ int po[NE + 1];
    __shared__ int cnt[NE];
    const int tid = threadIdx.x;
    if (tid == 0) {
        po[0] = 0;
        for (int e = 0; e < NE; ++e) {
            cnt[e] = counts[e];
            int pc = (cnt[e] + 127) & ~127;
            po[e + 1] = po[e] + pc;
        }
        for (int e = 0; e <= NE; ++e) poffset[e] = po[e];
        totalp[0] = po[NE];
    }
    __syncthreads();
    // fill padded tail rows with token 0 (their outputs are never combined)
    for (int e = 0; e < NE; ++e) {
        int base = po[e], c = cnt[e], pc = po[e + 1] - po[e];
        for (int i = c + tid; i < pc; i += 64) token_ids[base + i] = 0;
    }
}

__global__ __launch_bounds__(256) void scatter_rows(
    const int* __restrict__ idx_tk, const int* __restrict__ poffset,
    int* __restrict__ cursors, int* __restrict__ token_ids, int* __restrict__ t2r)
{
    int t = blockIdx.x * 256 + threadIdx.x;
    if (t >= T_TOK) return;
    for (int k = 0; k < 2; ++k) {
        int e = idx_tk[t * 2 + k];
        int pos = atomicAdd(&cursors[e], 1);
        int r = poffset[e] + pos;
        token_ids[r] = t;
        t2r[t * 2 + k] = r;
    }
}

// ---------------- expert GEMM: 128x128 tile, BK=64, bf16 MFMA 16x16x32, fp32 B converted on stage ----------------
template<bool GATHER, bool RELU, bool OUTBF16>
__global__ __launch_bounds__(256) void gemm_expert(
    const __bf16* __restrict__ A, int lda,
    const float* __restrict__ B, int Kdim, int N,
    const float* __restrict__ bias,
    void* __restrict__ Out, int ldo,
    const int* __restrict__ token_ids,
    const int* __restrict__ poffset,
    const int* __restrict__ totalp)
{
    __shared__ __bf16 As[128][72];  // +8 pad: 2-way bank aliasing only (free)
    __shared__ __bf16 Bt[128][72];  // transposed: Bt[n][k]
    const int tid = threadIdx.x;
    const int row0 = blockIdx.y * 128;
    if (row0 >= totalp[0]) return;
    int e = 0;
    while (e < NE - 1 && row0 >= poffset[e + 1]) ++e;
    const int n0 = blockIdx.x * 128;
    const float* Be = B + (size_t)e * Kdim * N;
    const float* biase = bias + (size_t)e * N;

    // A staging: thread -> (row = tid>>1, 32-elem half = tid&1); 64B per thread per kt
    const int arow = tid >> 1;
    const int ahalf = tid & 1;
    const int asrc = GATHER ? token_ids[row0 + arow] : (row0 + arow);
    const __bf16* aptr = A + (size_t)asrc * lda + ahalf * 32;

    // B staging: thread -> 8 k-rows (kb*8..) x 4 n-cols (nb*4..), transpose + fp32->bf16
    const int kb = tid >> 5;
    const int nb = tid & 31;

    const int lane = tid & 63;
    const int quad = lane >> 4;
    const int m16  = lane & 15;
    const int wave = tid >> 6;
    const int wm = wave >> 1, wn = wave & 1;  // 2x2 waves, each 64x64

    f32x4 acc[4][4];
    #pragma unroll
    for (int i = 0; i < 4; ++i)
        #pragma unroll
        for (int j = 0; j < 4; ++j)
            acc[i][j] = (f32x4){0.f, 0.f, 0.f, 0.f};

    const int niter = Kdim >> 6;
    for (int kt = 0; kt < niter; ++kt) {
        __syncthreads();
        {
            const uint4* p = (const uint4*)(aptr + kt * 64);
            uint4 v0 = p[0], v1 = p[1], v2 = p[2], v3 = p[3];
            *(uint4*)&As[arow][ahalf * 32 + 0]  = v0;
            *(uint4*)&As[arow][ahalf * 32 + 8]  = v1;
            *(uint4*)&As[arow][ahalf * 32 + 16] = v2;
            *(uint4*)&As[arow][ahalf * 32 + 24] = v3;
        }
        {
            const float* bp = Be + (size_t)(kt * 64 + kb * 8) * N + n0 + nb * 4;
            float4 f[8];
            #pragma unroll
            for (int kk = 0; kk < 8; ++kk) f[kk] = *(const float4*)(bp + (size_t)kk * N);
            #pragma unroll
            for (int j = 0; j < 4; ++j) {
                bf16x8 v;
                #pragma unroll
                for (int kk = 0; kk < 8; ++kk) v[kk] = (__bf16)((const float*)&f[kk])[j];
                *(bf16x8*)&Bt[nb * 4 + j][kb * 8] = v;
            }
        }
        __syncthreads();
        #pragma unroll
        for (int ks = 0; ks < 2; ++ks) {
            bf16x8 af[4], bfr[4];
            #pragma unroll
            for (int i = 0; i < 4; ++i)
                af[i] = *(const bf16x8*)&As[wm * 64 + i * 16 + m16][ks * 32 + quad * 8];
            #pragma unroll
            for (int j = 0; j < 4; ++j)
                bfr[j] = *(const bf16x8*)&Bt[wn * 64 + j * 16 + m16][ks * 32 + quad * 8];
            #pragma unroll
            for (int i = 0; i < 4; ++i)
                #pragma unroll
                for (int j = 0; j < 4; ++j)
                    acc[i][j] = __builtin_amdgcn_mfma_f32_16x16x32_bf16(af[i], bfr[j], acc[i][j], 0, 0, 0);
        }
    }
    // epilogue: C/D layout col=lane&15, row=quad*4+reg (verified m89/m91)
    #pragma unroll
    for (int i = 0; i < 4; ++i)
        #pragma unroll
        for (int j = 0; j < 4; ++j)
            #pragma unroll
            for (int r = 0; r < 4; ++r) {
                int grow = row0 + wm * 64 + i * 16 + quad * 4 + r;
                int gcol = n0 + wn * 64 + j * 16 + m16;
                float v = acc[i][j][r] + biase[gcol];
                if (RELU) v = v > 0.f ? v : 0.f;
                if (OUTBF16) ((__bf16*)Out)[(size_t)grow * ldo + gcol] = (__bf16)v;
                else         ((float*)Out)[(size_t)grow * ldo + gcol] = v;
            }
}

// ---------------- combine: out[t] = g0*y[r0] + g1*y[r1] ----------------
__global__ __launch_bounds__(256) void combine_out(
    const float* __restrict__ y, const float* __restrict__ gates_tk,
    const int* __restrict__ t2r, float* __restrict__ out)
{
    const int t = blockIdx.x;
    const int o = threadIdx.x * 4;
    const int r0 = t2r[t * 2], r1 = t2r[t * 2 + 1];
    const float g0 = gates_tk[t * 2], g1 = gates_tk[t * 2 + 1];
    float4 a = *(const float4*)&y[(size_t)r0 * O_DIM + o];
    float4 b = *(const float4*)&y[(size_t)r1 * O_DIM + o];
    float4 c;
    c.x = g0 * a.x + g1 * b.x;
    c.y = g0 * a.y + g1 * b.y;
    c.z = g0 * a.z + g1 * b.z;
    c.w = g0 * a.w + g1 * b.w;
    *(float4*)&out[(size_t)t * O_DIM + o] = c;
}

// ---------------- finalize aux outputs ----------------
__global__ void finalize_kernel(const double* __restrict__ prob_part,
                                const double* __restrict__ gsum_part,
                                float* __restrict__ out)
{
    __shared__ double ps[NE], gs[NE];
    const int tid = threadIdx.x;  // 64 threads
    if (tid < NE) {
        double p = 0.0, g = 0.0;
        for (int b = 0; b < 64; ++b) {
            p += prob_part[b * NE + tid];
            g += gsum_part[b * NE + tid];
        }
        ps[tid] = p / (double)T_TOK;
        gs[tid] = g / (double)T_TOK;
        out[(size_t)T_TOK * O_DIM + 1 + tid] = (float)(g / (double)T_TOK);
    }
    __syncthreads();
    if (tid == 0) {
        double lb = 0.0, ent = 0.0;
        for (int e = 0; e < NE; ++e) {
            lb += ps[e] * gs[e];
            ent -= ps[e] * log(ps[e] + 1e-8);
        }
        out[(size_t)T_TOK * O_DIM] = (float)(0.01 * 8.0 * lb);
        out[(size_t)T_TOK * O_DIM + 9] = (float)ent;
    }
}

// ---------------- launch ----------------
extern "C" void kernel_launch(void* const* d_in, const int* in_sizes, int n_in,
                              void* d_out, int out_size, void* d_ws, size_t ws_size,
                              hipStream_t stream)
{
    const float* x  = (const float*)d_in[0];
    const float* Wg = (const float*)d_in[1];
    const float* bg = (const float*)d_in[2];
    const float* W1 = (const float*)d_in[3];
    const float* b1 = (const float*)d_in[4];
    const float* W2 = (const float*)d_in[5];
    const float* b2 = (const float*)d_in[6];
    const float* W3 = (const float*)d_in[7];
    const float* b3 = (const float*)d_in[8];
    float* out = (float*)d_out;
    char* ws = (char*)d_ws;

    // workspace layout (~84 MB)
    __bf16* xb = (__bf16*)(ws + 0);                       //  8,388,608 B
    __bf16* h1 = (__bf16*)(ws + 8388608);                 // 37,748,736 B (9216x2048 bf16)
    float*  y  = (float*) (ws + 8388608);                 // aliases h1 (dead after layer2); 9216x1024 f32
    __bf16* h2 = (__bf16*)(ws + 46137344);                // 37,748,736 B
    float* gates_tk = (float*)(ws + 83886080);            // 32 KB
    int* idx_tk     = (int*)(ws + 83918848);              // 32 KB
    int* t2r        = (int*)(ws + 83951616);              // 32 KB
    int* token_ids  = (int*)(ws + 83984384);              // 36,864 B
    double* prob_part = (double*)(ws + 84021248);         // 4 KB
    double* gsum_part = (double*)(ws + 84025344);         // 4 KB
    char* small     = ws + 84029440;                      // 256 B control block
    int* counts     = (int*)(small + 0);
    int* cursors    = (int*)(small + 32);
    int* poffset    = (int*)(small + 64);
    int* totalp     = (int*)(small + 112);

    hipMemsetAsync(small, 0, 256, stream);
    gating_kernel<<<64, 64, 0, stream>>>(x, Wg, bg, xb, gates_tk, idx_tk,
                                         counts, prob_part, gsum_part);
    build_offsets<<<1, 64, 0, stream>>>(counts, poffset, totalp, token_ids);
    scatter_rows<<<16, 256, 0, stream>>>(idx_tk, poffset, cursors, token_ids, t2r);
    gemm_expert<true,  true,  true ><<<dim3(H_DIM / 128, RT128), 256, 0, stream>>>(
        xb, D_IN, W1, D_IN, H_DIM, b1, (void*)h1, H_DIM, token_ids, poffset, totalp);
    gemm_expert<false, true,  true ><<<dim3(H_DIM / 128, RT128), 256, 0, stream>>>(
        h1, H_DIM, W2, H_DIM, H_DIM, b2, (void*)h2, H_DIM, token_ids, poffset, totalp);
    gemm_expert<false, false, false><<<dim3(O_DIM / 128, RT128), 256, 0, stream>>>(
        h2, H_DIM, W3, H_DIM, O_DIM, b3, (void*)y, O_DIM, token_ids, poffset, totalp);
    combine_out<<<T_TOK, 256, 0, stream>>>(y, gates_tk, t2r, out);
    finalize_kernel<<<1, 64, 0, stream>>>(prob_part, gsum_part, out);
}

// Round 3
// 739.135 us; speedup vs baseline: 1.6059x; 1.1949x over previous
//
#include <hip/hip_runtime.h>
#include <hip/hip_bf16.h>
#include <math.h>

// Problem constants
#define T_TOK 4096   // B*S tokens
#define D_IN  1024
#define H_DIM 2048
#define O_DIM 1024
#define NE    8
#define ROWCAP 9216  // 8192 routed rows + per-expert pad to 128
#define RT128  72    // ROWCAP/128 row tiles

typedef __bf16 bf16x8 __attribute__((ext_vector_type(8)));
typedef __bf16 bf16x4 __attribute__((ext_vector_type(4)));
typedef float  f32x4  __attribute__((ext_vector_type(4)));

// async global->LDS, 16B per lane (HW: wave-uniform base + lane*16; our per-lane
// pointers are computed exactly in that order, so passing them per-lane matches)
__device__ __forceinline__ void gl_lds16(const void* g, void* l) {
    __builtin_amdgcn_global_load_lds(
        (const __attribute__((address_space(1))) void*)g,
        (__attribute__((address_space(3))) void*)l, 16, 0, 0);
}

// ---------------- gating: 8 threads/token, fp64 accumulate, shuffle reduce ----------------
__global__ __launch_bounds__(256) void gating_kernel(
    const float* __restrict__ x, const float* __restrict__ Wg, const float* __restrict__ bg,
    __bf16* __restrict__ xb, float* __restrict__ gates_tk, int* __restrict__ idx_tk,
    int* __restrict__ counts, double* __restrict__ prob_part, double* __restrict__ gsum_part)
{
    __shared__ float WgS[8][1032];   // [part][128 dims * 8 experts], +8 pad: parts land on different banks
    __shared__ float bgS[NE];
    __shared__ double tok_p[32][NE];
    __shared__ double tok_g[32][2];
    __shared__ int    tok_i[32][2];
    const int tid = threadIdx.x;

    // stage Wg (32KB) + bg
    for (int i = tid; i < D_IN * NE; i += 256)
        WgS[i >> 10][i & 1023] = Wg[i];
    if (tid < NE) bgS[tid] = bg[tid];

    // coalesced x -> bf16 for this block's 32-token slab
    {
        const size_t base = (size_t)blockIdx.x * 32 * D_IN;
        for (int i = tid * 4; i < 32 * D_IN; i += 256 * 4) {
            float4 v = *(const float4*)(x + base + i);
            bf16x4 b = {(__bf16)v.x, (__bf16)v.y, (__bf16)v.z, (__bf16)v.w};
            *(bf16x4*)(xb + base + i) = b;
        }
    }
    __syncthreads();

    const int tokL = tid >> 3;        // 0..31
    const int part = tid & 7;         // 0..7, owns dims [part*128, part*128+128)
    const int t = blockIdx.x * 32 + tokL;
    const float* xr = x + (size_t)t * D_IN + part * 128;

    double s[NE] = {0, 0, 0, 0, 0, 0, 0, 0};
    for (int j = 0; j < 128; j += 4) {
        float4 xv = *(const float4*)(xr + j);
        const float* w = &WgS[part][j * 8];
        #pragma unroll
        for (int jj = 0; jj < 4; ++jj) {
            double xd = (double)((&xv.x)[jj]);
            #pragma unroll
            for (int e = 0; e < NE; ++e)
                s[e] += xd * (double)w[jj * 8 + e];
        }
    }
    // reduce over the 8 parts (contiguous lanes)
    #pragma unroll
    for (int off = 4; off; off >>= 1)
        #pragma unroll
        for (int e = 0; e < NE; ++e)
            s[e] += __shfl_xor(s[e], off);

    if (part == 0) {
        double rg[NE];
        #pragma unroll
        for (int e = 0; e < NE; ++e) rg[e] = s[e] + (double)bgS[e];
        // top-2 (strict >, first index wins ties — matches lax.top_k)
        int i0 = 0;
        #pragma unroll
        for (int e = 1; e < NE; ++e) if (rg[e] > rg[i0]) i0 = e;
        int i1 = -1;
        #pragma unroll
        for (int e = 0; e < NE; ++e) {
            if (e == i0) continue;
            if (i1 < 0 || rg[e] > rg[i1]) i1 = e;
        }
        double e1 = exp(rg[i1] - rg[i0]);
        double den = 1.0 + e1;
        gates_tk[t * 2] = (float)(1.0 / den); gates_tk[t * 2 + 1] = (float)(e1 / den);
        idx_tk[t * 2] = i0;   idx_tk[t * 2 + 1] = i1;
        tok_g[tokL][0] = 1.0 / den; tok_g[tokL][1] = e1 / den;
        tok_i[tokL][0] = i0;        tok_i[tokL][1] = i1;
        // full softmax over 8 for aux losses
        double mx = rg[0];
        #pragma unroll
        for (int e = 1; e < NE; ++e) mx = fmax(mx, rg[e]);
        double pe[NE], sum = 0.0;
        #pragma unroll
        for (int e = 0; e < NE; ++e) { pe[e] = exp(rg[e] - mx); sum += pe[e]; }
        #pragma unroll
        for (int e = 0; e < NE; ++e) tok_p[tokL][e] = pe[e] / sum;
    }
    __syncthreads();
    if (tid < NE) {
        double p = 0.0, g = 0.0; int c = 0;
        for (int i = 0; i < 32; ++i) {
            p += tok_p[i][tid];
            if (tok_i[i][0] == tid) { g += tok_g[i][0]; ++c; }
            if (tok_i[i][1] == tid) { g += tok_g[i][1]; ++c; }
        }
        prob_part[blockIdx.x * NE + tid] = p;
        gsum_part[blockIdx.x * NE + tid] = g;
        atomicAdd(&counts[tid], c);
    }
}

// ---------------- weight transpose+convert: [K][N] fp32 -> [N][K] bf16 (per expert z) ----------------
__global__ __launch_bounds__(256) void transpose_cvt(
    const float* __restrict__ src, __bf16* __restrict__ dst, int K, int N)
{
    const int e = blockIdx.z;
    src += (size_t)e * K * N;
    dst += (size_t)e * N * K;
    const int k0 = blockIdx.y * 64, n0 = blockIdx.x * 64;
    __shared__ float tile[64][65];
    const int tid = threadIdx.x;
    const int r = tid >> 4;           // 0..15
    const int c = (tid & 15) * 4;
    #pragma unroll
    for (int i = 0; i < 4; ++i) {
        float4 v = *(const float4*)(src + (size_t)(k0 + r + i * 16) * N + n0 + c);
        tile[r + i * 16][c + 0] = v.x;
        tile[r + i * 16][c + 1] = v.y;
        tile[r + i * 16][c + 2] = v.z;
        tile[r + i * 16][c + 3] = v.w;
    }
    __syncthreads();
    const int n = tid >> 2;           // 0..63
    const int kc = (tid & 3) * 16;
    bf16x8 v0, v1;
    #pragma unroll
    for (int j = 0; j < 8; ++j) v0[j] = (__bf16)tile[kc + j][n];
    #pragma unroll
    for (int j = 0; j < 8; ++j) v1[j] = (__bf16)tile[kc + 8 + j][n];
    __bf16* dp = dst + (size_t)(n0 + n) * K + k0 + kc;
    *(bf16x8*)dp = v0;
    *(bf16x8*)(dp + 8) = v1;
}

// ---------------- routing: padded (to 128) prefix sums + tail fill ----------------
__global__ void build_offsets(const int* __restrict__ counts, int* __restrict__ poffset,
                              int* __restrict__ totalp, int* __restrict__ token_ids)
{
    __shared__ int po[NE + 1];
    __shared__ int cnt[NE];
    const int tid = threadIdx.x;
    if (tid == 0) {
        po[0] = 0;
        for (int e = 0; e < NE; ++e) {
            cnt[e] = counts[e];
            int pc = (cnt[e] + 127) & ~127;
            po[e + 1] = po[e] + pc;
        }
        for (int e = 0; e <= NE; ++e) poffset[e] = po[e];
        totalp[0] = po[NE];
    }
    __syncthreads();
    for (int e = 0; e < NE; ++e) {
        int base = po[e], c = cnt[e], pc = po[e + 1] - po[e];
        for (int i = c + tid; i < pc; i += 64) token_ids[base + i] = 0;
    }
}

__global__ __launch_bounds__(256) void scatter_rows(
    const int* __restrict__ idx_tk, const int* __restrict__ poffset,
    int* __restrict__ cursors, int* __restrict__ token_ids, int* __restrict__ t2r)
{
    int t = blockIdx.x * 256 + threadIdx.x;
    if (t >= T_TOK) return;
    for (int k = 0; k < 2; ++k) {
        int e = idx_tk[t * 2 + k];
        int pos = atomicAdd(&cursors[e], 1);
        int r = poffset[e] + pos;
        token_ids[r] = t;
        t2r[t * 2 + k] = r;
    }
}

// ---------------- expert GEMM (m97 structure): 128x128 tile, BK=64, global_load_lds staging ----------------
// A: [rows][Kdim] bf16 (gathered via token_ids for layer 1). Bt: [E][N][Kdim] bf16 (pre-transposed).
template<bool GATHER, bool RELU, bool OUTBF16>
__global__ __launch_bounds__(256) void gemm_expert(
    const __bf16* __restrict__ A, int lda,
    const __bf16* __restrict__ Bt, int Kdim, int N,
    const float* __restrict__ bias,
    void* __restrict__ Out, int ldo,
    const int* __restrict__ token_ids,
    const int* __restrict__ poffset,
    const int* __restrict__ totalp)
{
    __shared__ __bf16 As[128 * 64];   // contiguous, no pad (global_load_lds lane order)
    __shared__ __bf16 Bs[128 * 64];
    const int tid = threadIdx.x;
    const int row0 = blockIdx.y * 128;
    if (row0 >= totalp[0]) return;
    int e = 0;
    while (e < NE - 1 && row0 >= poffset[e + 1]) ++e;
    const int n0 = blockIdx.x * 128;
    const __bf16* Be = Bt + (size_t)e * Kdim * N;
    const float* biase = bias + (size_t)e * N;

    // staging map: call c stages rows [c*32, c*32+32); thread -> row c*32 + tid/8, col (tid&7)*8
    const int srow = tid >> 3;
    const int scol = (tid & 7) * 8;
    int arow_g[4];
    #pragma unroll
    for (int c = 0; c < 4; ++c) {
        int r = row0 + c * 32 + srow;
        arow_g[c] = GATHER ? token_ids[r] : r;
    }
    const __bf16* bbase = Be + (size_t)(n0 + srow) * Kdim + scol;

    const int lane = tid & 63;
    const int quad = lane >> 4;
    const int m16  = lane & 15;
    const int wave = tid >> 6;
    const int wm = wave >> 1, wn = wave & 1;  // 2x2 waves, each 64x64

    f32x4 acc[4][4];
    #pragma unroll
    for (int i = 0; i < 4; ++i)
        #pragma unroll
        for (int j = 0; j < 4; ++j)
            acc[i][j] = (f32x4){0.f, 0.f, 0.f, 0.f};

    const int niter = Kdim >> 6;
    for (int kt = 0; kt < niter; ++kt) {
        const int kofs = kt * 64 + scol;
        #pragma unroll
        for (int c = 0; c < 4; ++c)
            gl_lds16(A + (size_t)arow_g[c] * lda + kofs, (char*)As + c * 4096 + tid * 16);
        #pragma unroll
        for (int c = 0; c < 4; ++c)
            gl_lds16(bbase + (size_t)c * 32 * Kdim + kt * 64, (char*)Bs + c * 4096 + tid * 16);
        __syncthreads();   // drains vmcnt (compiler-inserted) — all tiles staged
        #pragma unroll
        for (int ks = 0; ks < 2; ++ks) {
            bf16x8 af[4], bfr[4];
            #pragma unroll
            for (int i = 0; i < 4; ++i)
                af[i] = *(const bf16x8*)&As[(wm * 64 + i * 16 + m16) * 64 + ks * 32 + quad * 8];
            #pragma unroll
            for (int j = 0; j < 4; ++j)
                bfr[j] = *(const bf16x8*)&Bs[(wn * 64 + j * 16 + m16) * 64 + ks * 32 + quad * 8];
            #pragma unroll
            for (int i = 0; i < 4; ++i)
                #pragma unroll
                for (int j = 0; j < 4; ++j)
                    acc[i][j] = __builtin_amdgcn_mfma_f32_16x16x32_bf16(af[i], bfr[j], acc[i][j], 0, 0, 0);
        }
        __syncthreads();   // all waves done reading before next stage overwrites
    }
    // epilogue: C/D layout col=lane&15, row=quad*4+reg (verified m89/m91)
    #pragma unroll
    for (int i = 0; i < 4; ++i)
        #pragma unroll
        for (int j = 0; j < 4; ++j)
            #pragma unroll
            for (int r = 0; r < 4; ++r) {
                int grow = row0 + wm * 64 + i * 16 + quad * 4 + r;
                int gcol = n0 + wn * 64 + j * 16 + m16;
                float v = acc[i][j][r] + biase[gcol];
                if (RELU) v = v > 0.f ? v : 0.f;
                if (OUTBF16) ((__bf16*)Out)[(size_t)grow * ldo + gcol] = (__bf16)v;
                else         ((float*)Out)[(size_t)grow * ldo + gcol] = v;
            }
}

// ---------------- combine: out[t] = g0*y[r0] + g1*y[r1] ----------------
__global__ __launch_bounds__(256) void combine_out(
    const float* __restrict__ y, const float* __restrict__ gates_tk,
    const int* __restrict__ t2r, float* __restrict__ out)
{
    const int t = blockIdx.x;
    const int o = threadIdx.x * 4;
    const int r0 = t2r[t * 2], r1 = t2r[t * 2 + 1];
    const float g0 = gates_tk[t * 2], g1 = gates_tk[t * 2 + 1];
    float4 a = *(const float4*)&y[(size_t)r0 * O_DIM + o];
    float4 b = *(const float4*)&y[(size_t)r1 * O_DIM + o];
    float4 c;
    c.x = g0 * a.x + g1 * b.x;
    c.y = g0 * a.y + g1 * b.y;
    c.z = g0 * a.z + g1 * b.z;
    c.w = g0 * a.w + g1 * b.w;
    *(float4*)&out[(size_t)t * O_DIM + o] = c;
}

// ---------------- finalize aux outputs ----------------
__global__ void finalize_kernel(const double* __restrict__ prob_part,
                                const double* __restrict__ gsum_part,
                                float* __restrict__ out)
{
    __shared__ double ps[NE], gs[NE];
    const int tid = threadIdx.x;  // 64 threads
    if (tid < NE) {
        double p = 0.0, g = 0.0;
        for (int b = 0; b < 128; ++b) {
            p += prob_part[b * NE + tid];
            g += gsum_part[b * NE + tid];
        }
        ps[tid] = p / (double)T_TOK;
        gs[tid] = g / (double)T_TOK;
        out[(size_t)T_TOK * O_DIM + 1 + tid] = (float)(g / (double)T_TOK);
    }
    __syncthreads();
    if (tid == 0) {
        double lb = 0.0, ent = 0.0;
        for (int e = 0; e < NE; ++e) {
            lb += ps[e] * gs[e];
            ent -= ps[e] * log(ps[e] + 1e-8);
        }
        out[(size_t)T_TOK * O_DIM] = (float)(0.01 * 8.0 * lb);
        out[(size_t)T_TOK * O_DIM + 9] = (float)ent;
    }
}

// ---------------- launch ----------------
extern "C" void kernel_launch(void* const* d_in, const int* in_sizes, int n_in,
                              void* d_out, int out_size, void* d_ws, size_t ws_size,
                              hipStream_t stream)
{
    const float* x  = (const float*)d_in[0];
    const float* Wg = (const float*)d_in[1];
    const float* bg = (const float*)d_in[2];
    const float* W1 = (const float*)d_in[3];
    const float* b1 = (const float*)d_in[4];
    const float* W2 = (const float*)d_in[5];
    const float* b2 = (const float*)d_in[6];
    const float* W3 = (const float*)d_in[7];
    const float* b3 = (const float*)d_in[8];
    float* out = (float*)d_out;
    char* ws = (char*)d_ws;

    // workspace layout (~219 MB)
    size_t off = 0;
    __bf16* xb  = (__bf16*)(ws + off); off += (size_t)T_TOK * D_IN * 2;          //  8,388,608
    __bf16* h1  = (__bf16*)(ws + off);
    float*  y   = (float*) (ws + off); off += (size_t)ROWCAP * H_DIM * 2;        // 37,748,736 (y aliases h1)
    __bf16* h2  = (__bf16*)(ws + off); off += (size_t)ROWCAP * H_DIM * 2;        // 37,748,736
    __bf16* W1t = (__bf16*)(ws + off); off += (size_t)NE * H_DIM * D_IN * 2;     // 33,554,432
    __bf16* W2t = (__bf16*)(ws + off); off += (size_t)NE * H_DIM * H_DIM * 2;    // 67,108,864
    __bf16* W3t = (__bf16*)(ws + off); off += (size_t)NE * O_DIM * H_DIM * 2;    // 33,554,432
    float* gates_tk = (float*)(ws + off); off += T_TOK * 2 * 4;
    int* idx_tk     = (int*)(ws + off);   off += T_TOK * 2 * 4;
    int* t2r        = (int*)(ws + off);   off += T_TOK * 2 * 4;
    int* token_ids  = (int*)(ws + off);   off += ROWCAP * 4;
    double* prob_part = (double*)(ws + off); off += 128 * NE * 8;
    double* gsum_part = (double*)(ws + off); off += 128 * NE * 8;
    char* small     = ws + off;
    int* counts     = (int*)(small + 0);
    int* cursors    = (int*)(small + 32);
    int* poffset    = (int*)(small + 64);
    int* totalp     = (int*)(small + 112);

    hipMemsetAsync(small, 0, 256, stream);
    gating_kernel<<<128, 256, 0, stream>>>(x, Wg, bg, xb, gates_tk, idx_tk,
                                           counts, prob_part, gsum_part);
    transpose_cvt<<<dim3(H_DIM / 64, D_IN / 64, NE), 256, 0, stream>>>(W1, W1t, D_IN, H_DIM);
    transpose_cvt<<<dim3(H_DIM / 64, H_DIM / 64, NE), 256, 0, stream>>>(W2, W2t, H_DIM, H_DIM);
    transpose_cvt<<<dim3(O_DIM / 64, H_DIM / 64, NE), 256, 0, stream>>>(W3, W3t, H_DIM, O_DIM);
    build_offsets<<<1, 64, 0, stream>>>(counts, poffset, totalp, token_ids);
    scatter_rows<<<16, 256, 0, stream>>>(idx_tk, poffset, cursors, token_ids, t2r);
    gemm_expert<true,  true,  true ><<<dim3(H_DIM / 128, RT128), 256, 0, stream>>>(
        xb, D_IN, W1t, D_IN, H_DIM, b1, (void*)h1, H_DIM, token_ids, poffset, totalp);
    gemm_expert<false, true,  true ><<<dim3(H_DIM / 128, RT128), 256, 0, stream>>>(
        h1, H_DIM, W2t, H_DIM, H_DIM, b2, (void*)h2, H_DIM, token_ids, poffset, totalp);
    gemm_expert<false, false, false><<<dim3(O_DIM / 128, RT128), 256, 0, stream>>>(
        h2, H_DIM, W3t, H_DIM, O_DIM, b3, (void*)y, O_DIM, token_ids, poffset, totalp);
    combine_out<<<T_TOK, 256, 0, stream>>>(y, gates_tk, t2r, out);
    finalize_kernel<<<1, 64, 0, stream>>>(prob_part, gsum_part, out);
}

// Round 4
// 641.870 us; speedup vs baseline: 1.8493x; 1.1515x over previous
//
#include <hip/hip_runtime.h>
#include <hip/hip_bf16.h>
#include <math.h>

// Problem constants
#define T_TOK 4096   // B*S tokens
#define D_IN  1024
#define H_DIM 2048
#define O_DIM 1024
#define NE    8
#define ROWCAP 9216  // 8192 routed rows + per-expert pad to 128
#define RT128  72    // ROWCAP/128 row tiles

typedef __bf16 bf16x8 __attribute__((ext_vector_type(8)));
typedef __bf16 bf16x4 __attribute__((ext_vector_type(4)));
typedef float  f32x4  __attribute__((ext_vector_type(4)));

// async global->LDS, 16B per lane (HW: wave-uniform base + lane*16)
__device__ __forceinline__ void gl_lds16(const void* g, void* l) {
    __builtin_amdgcn_global_load_lds(
        (const __attribute__((address_space(1))) void*)g,
        (__attribute__((address_space(3))) void*)l, 16, 0, 0);
}

// ---------------- gating: 8 threads/token, fp64 accumulate, shuffle reduce ----------------
__global__ __launch_bounds__(256) void gating_kernel(
    const float* __restrict__ x, const float* __restrict__ Wg, const float* __restrict__ bg,
    __bf16* __restrict__ xb, float* __restrict__ gates_tk, int* __restrict__ idx_tk,
    int* __restrict__ counts, double* __restrict__ prob_part, double* __restrict__ gsum_part)
{
    __shared__ float WgS[8][1032];   // [part][128 dims * 8 experts], +8 pad
    __shared__ float bgS[NE];
    __shared__ double tok_p[32][NE];
    __shared__ double tok_g[32][2];
    __shared__ int    tok_i[32][2];
    const int tid = threadIdx.x;

    for (int i = tid; i < D_IN * NE; i += 256)
        WgS[i >> 10][i & 1023] = Wg[i];
    if (tid < NE) bgS[tid] = bg[tid];

    {
        const size_t base = (size_t)blockIdx.x * 32 * D_IN;
        for (int i = tid * 4; i < 32 * D_IN; i += 256 * 4) {
            float4 v = *(const float4*)(x + base + i);
            bf16x4 b = {(__bf16)v.x, (__bf16)v.y, (__bf16)v.z, (__bf16)v.w};
            *(bf16x4*)(xb + base + i) = b;
        }
    }
    __syncthreads();

    const int tokL = tid >> 3;
    const int part = tid & 7;
    const int t = blockIdx.x * 32 + tokL;
    const float* xr = x + (size_t)t * D_IN + part * 128;

    double s[NE] = {0, 0, 0, 0, 0, 0, 0, 0};
    for (int j = 0; j < 128; j += 4) {
        float4 xv = *(const float4*)(xr + j);
        const float* w = &WgS[part][j * 8];
        #pragma unroll
        for (int jj = 0; jj < 4; ++jj) {
            double xd = (double)((&xv.x)[jj]);
            #pragma unroll
            for (int e = 0; e < NE; ++e)
                s[e] += xd * (double)w[jj * 8 + e];
        }
    }
    #pragma unroll
    for (int off = 4; off; off >>= 1)
        #pragma unroll
        for (int e = 0; e < NE; ++e)
            s[e] += __shfl_xor(s[e], off);

    if (part == 0) {
        double rg[NE];
        #pragma unroll
        for (int e = 0; e < NE; ++e) rg[e] = s[e] + (double)bgS[e];
        int i0 = 0;
        #pragma unroll
        for (int e = 1; e < NE; ++e) if (rg[e] > rg[i0]) i0 = e;
        int i1 = -1;
        #pragma unroll
        for (int e = 0; e < NE; ++e) {
            if (e == i0) continue;
            if (i1 < 0 || rg[e] > rg[i1]) i1 = e;
        }
        double e1 = exp(rg[i1] - rg[i0]);
        double den = 1.0 + e1;
        gates_tk[t * 2] = (float)(1.0 / den); gates_tk[t * 2 + 1] = (float)(e1 / den);
        idx_tk[t * 2] = i0;   idx_tk[t * 2 + 1] = i1;
        tok_g[tokL][0] = 1.0 / den; tok_g[tokL][1] = e1 / den;
        tok_i[tokL][0] = i0;        tok_i[tokL][1] = i1;
        double mx = rg[0];
        #pragma unroll
        for (int e = 1; e < NE; ++e) mx = fmax(mx, rg[e]);
        double pe[NE], sum = 0.0;
        #pragma unroll
        for (int e = 0; e < NE; ++e) { pe[e] = exp(rg[e] - mx); sum += pe[e]; }
        #pragma unroll
        for (int e = 0; e < NE; ++e) tok_p[tokL][e] = pe[e] / sum;
    }
    __syncthreads();
    if (tid < NE) {
        double p = 0.0, g = 0.0; int c = 0;
        for (int i = 0; i < 32; ++i) {
            p += tok_p[i][tid];
            if (tok_i[i][0] == tid) { g += tok_g[i][0]; ++c; }
            if (tok_i[i][1] == tid) { g += tok_g[i][1]; ++c; }
        }
        prob_part[blockIdx.x * NE + tid] = p;
        gsum_part[blockIdx.x * NE + tid] = g;
        atomicAdd(&counts[tid], c);
    }
}

// ---------------- weight transpose+convert: [K][N] fp32 -> [N][K] bf16 (per expert z) ----------------
__global__ __launch_bounds__(256) void transpose_cvt(
    const float* __restrict__ src, __bf16* __restrict__ dst, int K, int N)
{
    const int e = blockIdx.z;
    src += (size_t)e * K * N;
    dst += (size_t)e * N * K;
    const int k0 = blockIdx.y * 64, n0 = blockIdx.x * 64;
    __shared__ float tile[64][65];
    const int tid = threadIdx.x;
    const int r = tid >> 4;
    const int c = (tid & 15) * 4;
    #pragma unroll
    for (int i = 0; i < 4; ++i) {
        float4 v = *(const float4*)(src + (size_t)(k0 + r + i * 16) * N + n0 + c);
        tile[r + i * 16][c + 0] = v.x;
        tile[r + i * 16][c + 1] = v.y;
        tile[r + i * 16][c + 2] = v.z;
        tile[r + i * 16][c + 3] = v.w;
    }
    __syncthreads();
    const int n = tid >> 2;
    const int kc = (tid & 3) * 16;
    bf16x8 v0, v1;
    #pragma unroll
    for (int j = 0; j < 8; ++j) v0[j] = (__bf16)tile[kc + j][n];
    #pragma unroll
    for (int j = 0; j < 8; ++j) v1[j] = (__bf16)tile[kc + 8 + j][n];
    __bf16* dp = dst + (size_t)(n0 + n) * K + k0 + kc;
    *(bf16x8*)dp = v0;
    *(bf16x8*)(dp + 8) = v1;
}

// ---------------- routing: padded (to 128) prefix sums + tail fill ----------------
__global__ void build_offsets(const int* __restrict__ counts, int* __restrict__ poffset,
                              int* __restrict__ totalp, int* __restrict__ token_ids)
{
    __shared__ int po[NE + 1];
    __shared__ int cnt[NE];
    const int tid = threadIdx.x;
    if (tid == 0) {
        po[0] = 0;
        for (int e = 0; e < NE; ++e) {
            cnt[e] = counts[e];
            int pc = (cnt[e] + 127) & ~127;
            po[e + 1] = po[e] + pc;
        }
        for (int e = 0; e <= NE; ++e) poffset[e] = po[e];
        totalp[0] = po[NE];
    }
    __syncthreads();
    for (int e = 0; e < NE; ++e) {
        int base = po[e], c = cnt[e], pc = po[e + 1] - po[e];
        for (int i = c + tid; i < pc; i += 64) token_ids[base + i] = 0;
    }
}

__global__ __launch_bounds__(256) void scatter_rows(
    const int* __restrict__ idx_tk, const int* __restrict__ poffset,
    int* __restrict__ cursors, int* __restrict__ token_ids, int* __restrict__ t2r)
{
    int t = blockIdx.x * 256 + threadIdx.x;
    if (t >= T_TOK) return;
    for (int k = 0; k < 2; ++k) {
        int e = idx_tk[t * 2 + k];
        int pos = atomicAdd(&cursors[e], 1);
        int r = poffset[e] + pos;
        token_ids[r] = t;
        t2r[t * 2 + k] = r;
    }
}

// ---------------- expert GEMM: 128x128 tile, BK=64, global_load_lds, XOR-swizzled LDS ----------------
// LDS layout: 16B chunk j of row r stored at physical chunk (j ^ (r&7)).
// Staging thread writes LDS chunk (tid&7) of row (c*32 + tid>>3) -> loads global chunk (tid&7)^((tid>>3)&7).
// Fragment read of logical chunk (ks*4+quad) of row rr -> physical (ks*4+quad)^(rr&7), rr&7 == m16&7.
template<bool GATHER, bool RELU, bool OUTBF16>
__global__ __launch_bounds__(256) void gemm_expert(
    const __bf16* __restrict__ A, int lda,
    const __bf16* __restrict__ Bt, int Kdim, int N,
    const float* __restrict__ bias,
    void* __restrict__ Out, int ldo,
    const int* __restrict__ token_ids,
    const int* __restrict__ poffset,
    const int* __restrict__ totalp)
{
    __shared__ __bf16 As[128 * 64];
    __shared__ __bf16 Bs[128 * 64];
    const int tid = threadIdx.x;
    const int row0 = blockIdx.y * 128;
    if (row0 >= totalp[0]) return;
    int e = 0;
    while (e < NE - 1 && row0 >= poffset[e + 1]) ++e;
    const int n0 = blockIdx.x * 128;
    const __bf16* Be = Bt + (size_t)e * Kdim * N;
    const float* biase = bias + (size_t)e * N;

    const int srow = tid >> 3;
    const int jperm = (tid & 7) ^ (srow & 7);   // XOR-swizzled source chunk
    const int scol = jperm * 8;                 // element offset within 64-wide K slice
    int arow_g[4];
    #pragma unroll
    for (int c = 0; c < 4; ++c) {
        int r = row0 + c * 32 + srow;
        arow_g[c] = GATHER ? token_ids[r] : r;
    }
    const __bf16* bbase = Be + (size_t)(n0 + srow) * Kdim + scol;

    const int lane = tid & 63;
    const int quad = lane >> 4;
    const int m16  = lane & 15;
    const int wave = tid >> 6;
    const int wm = wave >> 1, wn = wave & 1;

    f32x4 acc[4][4];
    #pragma unroll
    for (int i = 0; i < 4; ++i)
        #pragma unroll
        for (int j = 0; j < 4; ++j)
            acc[i][j] = (f32x4){0.f, 0.f, 0.f, 0.f};

    const int niter = Kdim >> 6;
    for (int kt = 0; kt < niter; ++kt) {
        const int kofs = kt * 64 + scol;
        #pragma unroll
        for (int c = 0; c < 4; ++c)
            gl_lds16(A + (size_t)arow_g[c] * lda + kofs, (char*)As + c * 4096 + tid * 16);
        #pragma unroll
        for (int c = 0; c < 4; ++c)
            gl_lds16(bbase + (size_t)c * 32 * Kdim + kt * 64, (char*)Bs + c * 4096 + tid * 16);
        __syncthreads();
        #pragma unroll
        for (int ks = 0; ks < 2; ++ks) {
            const int p = ((ks << 2) | quad) ^ (m16 & 7);   // physical chunk after swizzle
            bf16x8 af[4], bfr[4];
            #pragma unroll
            for (int i = 0; i < 4; ++i)
                af[i] = *(const bf16x8*)&As[(wm * 64 + i * 16 + m16) * 64 + p * 8];
            #pragma unroll
            for (int j = 0; j < 4; ++j)
                bfr[j] = *(const bf16x8*)&Bs[(wn * 64 + j * 16 + m16) * 64 + p * 8];
            #pragma unroll
            for (int i = 0; i < 4; ++i)
                #pragma unroll
                for (int j = 0; j < 4; ++j)
                    acc[i][j] = __builtin_amdgcn_mfma_f32_16x16x32_bf16(af[i], bfr[j], acc[i][j], 0, 0, 0);
        }
        __syncthreads();
    }
    #pragma unroll
    for (int i = 0; i < 4; ++i)
        #pragma unroll
        for (int j = 0; j < 4; ++j)
            #pragma unroll
            for (int r = 0; r < 4; ++r) {
                int grow = row0 + wm * 64 + i * 16 + quad * 4 + r;
                int gcol = n0 + wn * 64 + j * 16 + m16;
                float v = acc[i][j][r] + biase[gcol];
                if (RELU) v = v > 0.f ? v : 0.f;
                if (OUTBF16) ((__bf16*)Out)[(size_t)grow * ldo + gcol] = (__bf16)v;
                else         ((float*)Out)[(size_t)grow * ldo + gcol] = v;
            }
}

// ---------------- combine: out[t] = g0*y[r0] + g1*y[r1] ----------------
__global__ __launch_bounds__(256) void combine_out(
    const float* __restrict__ y, const float* __restrict__ gates_tk,
    const int* __restrict__ t2r, float* __restrict__ out)
{
    const int t = blockIdx.x;
    const int o = threadIdx.x * 4;
    const int r0 = t2r[t * 2], r1 = t2r[t * 2 + 1];
    const float g0 = gates_tk[t * 2], g1 = gates_tk[t * 2 + 1];
    float4 a = *(const float4*)&y[(size_t)r0 * O_DIM + o];
    float4 b = *(const float4*)&y[(size_t)r1 * O_DIM + o];
    float4 c;
    c.x = g0 * a.x + g1 * b.x;
    c.y = g0 * a.y + g1 * b.y;
    c.z = g0 * a.z + g1 * b.z;
    c.w = g0 * a.w + g1 * b.w;
    *(float4*)&out[(size_t)t * O_DIM + o] = c;
}

// ---------------- finalize aux outputs ----------------
__global__ void finalize_kernel(const double* __restrict__ prob_part,
                                const double* __restrict__ gsum_part,
                                float* __restrict__ out)
{
    __shared__ double ps[NE], gs[NE];
    const int tid = threadIdx.x;
    if (tid < NE) {
        double p = 0.0, g = 0.0;
        for (int b = 0; b < 128; ++b) {
            p += prob_part[b * NE + tid];
            g += gsum_part[b * NE + tid];
        }
        ps[tid] = p / (double)T_TOK;
        gs[tid] = g / (double)T_TOK;
        out[(size_t)T_TOK * O_DIM + 1 + tid] = (float)(g / (double)T_TOK);
    }
    __syncthreads();
    if (tid == 0) {
        double lb = 0.0, ent = 0.0;
        for (int e = 0; e < NE; ++e) {
            lb += ps[e] * gs[e];
            ent -= ps[e] * log(ps[e] + 1e-8);
        }
        out[(size_t)T_TOK * O_DIM] = (float)(0.01 * 8.0 * lb);
        out[(size_t)T_TOK * O_DIM + 9] = (float)ent;
    }
}

// ---------------- launch ----------------
extern "C" void kernel_launch(void* const* d_in, const int* in_sizes, int n_in,
                              void* d_out, int out_size, void* d_ws, size_t ws_size,
                              hipStream_t stream)
{
    const float* x  = (const float*)d_in[0];
    const float* Wg = (const float*)d_in[1];
    const float* bg = (const float*)d_in[2];
    const float* W1 = (const float*)d_in[3];
    const float* b1 = (const float*)d_in[4];
    const float* W2 = (const float*)d_in[5];
    const float* b2 = (const float*)d_in[6];
    const float* W3 = (const float*)d_in[7];
    const float* b3 = (const float*)d_in[8];
    float* out = (float*)d_out;
    char* ws = (char*)d_ws;

    size_t off = 0;
    __bf16* xb  = (__bf16*)(ws + off); off += (size_t)T_TOK * D_IN * 2;
    __bf16* h1  = (__bf16*)(ws + off);
    float*  y   = (float*) (ws + off); off += (size_t)ROWCAP * H_DIM * 2;
    __bf16* h2  = (__bf16*)(ws + off); off += (size_t)ROWCAP * H_DIM * 2;
    __bf16* W1t = (__bf16*)(ws + off); off += (size_t)NE * H_DIM * D_IN * 2;
    __bf16* W2t = (__bf16*)(ws + off); off += (size_t)NE * H_DIM * H_DIM * 2;
    __bf16* W3t = (__bf16*)(ws + off); off += (size_t)NE * O_DIM * H_DIM * 2;
    float* gates_tk = (float*)(ws + off); off += T_TOK * 2 * 4;
    int* idx_tk     = (int*)(ws + off);   off += T_TOK * 2 * 4;
    int* t2r        = (int*)(ws + off);   off += T_TOK * 2 * 4;
    int* token_ids  = (int*)(ws + off);   off += ROWCAP * 4;
    double* prob_part = (double*)(ws + off); off += 128 * NE * 8;
    double* gsum_part = (double*)(ws + off); off += 128 * NE * 8;
    char* small     = ws + off;
    int* counts     = (int*)(small + 0);
    int* cursors    = (int*)(small + 32);
    int* poffset    = (int*)(small + 64);
    int* totalp     = (int*)(small + 112);

    hipMemsetAsync(small, 0, 256, stream);
    gating_kernel<<<128, 256, 0, stream>>>(x, Wg, bg, xb, gates_tk, idx_tk,
                                           counts, prob_part, gsum_part);
    transpose_cvt<<<dim3(H_DIM / 64, D_IN / 64, NE), 256, 0, stream>>>(W1, W1t, D_IN, H_DIM);
    transpose_cvt<<<dim3(H_DIM / 64, H_DIM / 64, NE), 256, 0, stream>>>(W2, W2t, H_DIM, H_DIM);
    transpose_cvt<<<dim3(O_DIM / 64, H_DIM / 64, NE), 256, 0, stream>>>(W3, W3t, H_DIM, O_DIM);
    build_offsets<<<1, 64, 0, stream>>>(counts, poffset, totalp, token_ids);
    scatter_rows<<<16, 256, 0, stream>>>(idx_tk, poffset, cursors, token_ids, t2r);
    gemm_expert<true,  true,  true ><<<dim3(H_DIM / 128, RT128), 256, 0, stream>>>(
        xb, D_IN, W1t, D_IN, H_DIM, b1, (void*)h1, H_DIM, token_ids, poffset, totalp);
    gemm_expert<false, true,  true ><<<dim3(H_DIM / 128, RT128), 256, 0, stream>>>(
        h1, H_DIM, W2t, H_DIM, H_DIM, b2, (void*)h2, H_DIM, token_ids, poffset, totalp);
    gemm_expert<false, false, false><<<dim3(O_DIM / 128, RT128), 256, 0, stream>>>(
        h2, H_DIM, W3t, H_DIM, O_DIM, b3, (void*)y, O_DIM, token_ids, poffset, totalp);
    combine_out<<<T_TOK, 256, 0, stream>>>(y, gates_tk, t2r, out);
    finalize_kernel<<<1, 64, 0, stream>>>(prob_part, gsum_part, out);
}